// Round 10
// baseline (724.291 us; speedup 1.0000x reference)
//
#include <hip/hip_runtime.h>
#include <hip/hip_fp16.h>

// TriangleMultiplicationOutgoing — MI355X (gfx950)
// ROUND 14: round-13 resubmit; fix = __builtin_nontemporal_store requires a
// NATIVE vector type (ext_vector_type), not HIP_vector_type uint4. Theory
// unchanged: pass2 bound by L2<->HBM churn; o16 (zero reuse in-pass) must not
// allocate in L2. nt stores -> WRITE ~64MB, L2 freed for A/B panels.
// Everything else byte-identical to round 12/13 verified passes.

typedef unsigned short u16;
typedef unsigned int u32;
typedef unsigned short u16x8 __attribute__((ext_vector_type(8)));
typedef unsigned int u32x4 __attribute__((ext_vector_type(4)));
typedef _Float16 f16;
typedef _Float16 f16x8 __attribute__((ext_vector_type(8)));
typedef _Float16 f16x2 __attribute__((ext_vector_type(2)));
typedef float f32x4 __attribute__((ext_vector_type(4)));

#define NROW 262144  // 512*512 spatial positions
#define CH 128

__device__ __forceinline__ float sigmoidf_(float x) {
  return 1.0f / (1.0f + __expf(-x));
}

// ---------------- pass 0: weights fp32 -> fp16, order [pa, ga, pb, gb] ------
__global__ __launch_bounds__(256) void k_pass0(
    const float* __restrict__ wpa, const float* __restrict__ wga,
    const float* __restrict__ wpb, const float* __restrict__ wgb,
    f16* __restrict__ wq) {
  const int m = blockIdx.x >> 6;
  const int idx = ((blockIdx.x & 63) << 8) + threadIdx.x;
  const float* src = (m == 0) ? wpa : (m == 1) ? wga : (m == 2) ? wpb : wgb;
  wq[(size_t)m * CH * CH + idx] = (f16)src[idx];
}

// ---------------- cvt2: w_g, w_o fp32 -> fp16 (into ws head) ----------------
__global__ __launch_bounds__(256) void k_cvt2(
    const float* __restrict__ w_g, const float* __restrict__ w_o,
    f16* __restrict__ wq3) {
  const int m = blockIdx.x >> 6;
  const int idx = ((blockIdx.x & 63) << 8) + threadIdx.x;
  const float* src = (m == 0) ? w_g : w_o;
  wq3[(size_t)m * CH * CH + idx] = (f16)src[idx];
}

// ---------------- pass 1: LN(z) + 4 projections -> a,b (fp16, [c][r]) -------
// UNCHANGED from verified round-9 build.
__global__ __launch_bounds__(256) void k_pass1(
    const float* __restrict__ z, const float* __restrict__ pm,
    const float* __restrict__ lnw, const float* __restrict__ lnb,
    const f16* __restrict__ wq,
    f16* __restrict__ a_t, f16* __restrict__ b_t) {
  __shared__ __attribute__((aligned(16))) f16 zn[64 * CH];  // 16 KB
  __shared__ __attribute__((aligned(16))) f16 ab[CH * 64];  // 16 KB (one pair)
  __shared__ float pmv[64];
  const int t = threadIdx.x, lane = t & 63, w = t >> 6;
  const size_t r0 = (size_t)blockIdx.x * 64;

  {
    const int rr = lane >> 4, q = lane & 15;
    const float4 lw0 = *(const float4*)(lnw + q * 8);
    const float4 lw1 = *(const float4*)(lnw + q * 8 + 4);
    const float4 lb0 = *(const float4*)(lnb + q * 8);
    const float4 lb1 = *(const float4*)(lnb + q * 8 + 4);
    for (int it = 0; it < 4; it++) {
      const int row = w * 16 + it * 4 + rr;
      const float* src = z + (r0 + row) * CH + q * 8;
      const float4 v0 = *(const float4*)(src);
      const float4 v1 = *(const float4*)(src + 4);
      float s = v0.x + v0.y + v0.z + v0.w + v1.x + v1.y + v1.z + v1.w;
      float sq = v0.x * v0.x + v0.y * v0.y + v0.z * v0.z + v0.w * v0.w +
                 v1.x * v1.x + v1.y * v1.y + v1.z * v1.z + v1.w * v1.w;
#pragma unroll
      for (int off = 8; off > 0; off >>= 1) {
        s += __shfl_xor(s, off);
        sq += __shfl_xor(sq, off);
      }
      const float mu = s * (1.0f / 128.0f);
      const float rs = rsqrtf(sq * (1.0f / 128.0f) - mu * mu + 1e-5f);
      f16x8 p;
      p[0] = (f16)((v0.x - mu) * rs * lw0.x + lb0.x);
      p[1] = (f16)((v0.y - mu) * rs * lw0.y + lb0.y);
      p[2] = (f16)((v0.z - mu) * rs * lw0.z + lb0.z);
      p[3] = (f16)((v0.w - mu) * rs * lw0.w + lb0.w);
      p[4] = (f16)((v1.x - mu) * rs * lw1.x + lb1.x);
      p[5] = (f16)((v1.y - mu) * rs * lw1.y + lb1.y);
      p[6] = (f16)((v1.z - mu) * rs * lw1.z + lb1.z);
      p[7] = (f16)((v1.w - mu) * rs * lw1.w + lb1.w);
      const int byte = (row * 256 + q * 16) ^ ((row & 7) << 4);
      *(f16x8*)((char*)zn + byte) = p;
      if (q == 0) pmv[row] = pm[r0 + row];
    }
  }
  __syncthreads();

  const int g = lane >> 4, ln16 = lane & 15;
#pragma unroll
  for (int pair = 0; pair < 2; pair++) {
    const f16* __restrict__ wp = wq + (size_t)(pair * 2 + 0) * CH * CH;
    const f16* __restrict__ wgp = wq + (size_t)(pair * 2 + 1) * CH * CH;
#pragma unroll
    for (int f = 0; f < 2; f++) {
      const int col = w * 32 + f * 16 + ln16;
      f16x8 bp[4], bg[4];
#pragma unroll
      for (int ks = 0; ks < 4; ks++) {
        const size_t wo = (size_t)col * CH + ks * 32 + g * 8;
        bp[ks] = *(const f16x8*)(wp + wo);
        bg[ks] = *(const f16x8*)(wgp + wo);
      }
#pragma unroll
      for (int mt = 0; mt < 4; mt++) {
        const int m0 = mt * 16;
        const int row = m0 + ln16;
        f32x4 accP = {0.f, 0.f, 0.f, 0.f}, accG = {0.f, 0.f, 0.f, 0.f};
#pragma unroll
        for (int ks = 0; ks < 4; ks++) {
          const int byte =
              (row * 256 + (ks * 32 + g * 8) * 2) ^ ((row & 7) << 4);
          const f16x8 af = *(const f16x8*)((const char*)zn + byte);
          accP = __builtin_amdgcn_mfma_f32_16x16x32_f16(af, bp[ks], accP, 0, 0, 0);
          accG = __builtin_amdgcn_mfma_f32_16x16x32_f16(af, bg[ks], accG, 0, 0, 0);
        }
        uint2 pk;
        {
          const int rbase = m0 + g * 4;
          const float v0 = pmv[rbase + 0] * sigmoidf_(accG[0]) * accP[0];
          const float v1 = pmv[rbase + 1] * sigmoidf_(accG[1]) * accP[1];
          const float v2 = pmv[rbase + 2] * sigmoidf_(accG[2]) * accP[2];
          const float v3 = pmv[rbase + 3] * sigmoidf_(accG[3]) * accP[3];
          f16x2 h01, h23;
          h01.x = (f16)v0; h01.y = (f16)v1;
          h23.x = (f16)v2; h23.y = (f16)v3;
          pk.x = *(u32*)&h01;
          pk.y = *(u32*)&h23;
        }
        const int byte = ((col * 64 + m0 + g * 4) * 2) ^ ((col & 7) << 4);
        *(uint2*)((char*)ab + byte) = pk;
      }
    }
    __syncthreads();
    {
      const int o = t >> 1, h = t & 1;
      f16* __restrict__ dst =
          (pair ? b_t : a_t) + (size_t)o * NROW + r0 + h * 32;
#pragma unroll
      for (int e = 0; e < 4; e++) {
        const int byte = ((o * 64 + h * 32 + e * 8) * 2) ^ ((o & 7) << 4);
        *(uint4*)(dst + e * 8) = *(const uint4*)((const char*)ab + byte);
      }
    }
    if (pair == 0) __syncthreads();
  }
}

// ------- pass 2: o16[c][i,j] = sum_k a[i,k,c]*b[j,k,c]  (MFMA fp16 GEMM) ----
// Per channel c: O_c(512x512) = A_c * B_c^T, output fp16 channel-major.
// Remap: xcd=bx&7, c = xcd + 8*(k>>4), T = k&15 -> all 16 tiles of a channel
// consecutive on one XCD. o16 written with NONTEMPORAL stores (no L2 alloc).
__global__ __launch_bounds__(256, 4) void k_pass2(
    const f16* __restrict__ a_t, const f16* __restrict__ b_t,
    f16* __restrict__ o16) {
  __shared__ __attribute__((aligned(16))) f16 smem[2 * 128 * 64];  // 32 KB
  f16* At = smem;              // 128 rows x 64 halfs (XOR-swizzled)
  f16* Bt = smem + 128 * 64;
  const int t = threadIdx.x, lane = t & 63, w = t >> 6;
  const int bx = blockIdx.x;
  const int xcd = bx & 7, k = bx >> 3;
  const int T = k & 15, cc = k >> 4;
  const int c = xcd + (cc << 3);
  const int i0 = (T >> 2) * 128, j0 = (T & 3) * 128;
  const int wr = w >> 1, wc = w & 1;
  const int g = lane >> 4, ln16 = lane & 15;

  const f16* __restrict__ Ab = a_t + (size_t)c * NROW + (size_t)i0 * 512;
  const f16* __restrict__ Bb = b_t + (size_t)c * NROW + (size_t)j0 * 512;

  // staging: thread t -> row t>>1 (0..127), half t&1 (32 halfs of k)
  const int srow = t >> 1, shalf = t & 1;
  const f16* __restrict__ gA = Ab + (size_t)srow * 512 + shalf * 32;
  const f16* __restrict__ gB = Bb + (size_t)srow * 512 + shalf * 32;
  int swb[4];
#pragma unroll
  for (int q = 0; q < 4; q++)
    swb[q] = srow * 128 + ((shalf * 64 + q * 16) ^ ((srow & 7) << 4));

  f32x4 acc[4][4];
#pragma unroll
  for (int mt = 0; mt < 4; mt++)
#pragma unroll
    for (int nt = 0; nt < 4; nt++) acc[mt][nt] = {0.f, 0.f, 0.f, 0.f};

  uint4 va[4], vb[4];
#pragma unroll
  for (int q = 0; q < 4; q++) {
    va[q] = *(const uint4*)(gA + q * 8);
    vb[q] = *(const uint4*)(gB + q * 8);
  }
#pragma unroll
  for (int q = 0; q < 4; q++) {
    *(uint4*)((char*)At + swb[q]) = va[q];
    *(uint4*)((char*)Bt + swb[q]) = vb[q];
  }
  __syncthreads();

  for (int ks = 0; ks < 8; ks++) {
    const bool more = (ks + 1) < 8;
    if (more) {  // issue next K-step's global loads early (T14)
#pragma unroll
      for (int q = 0; q < 4; q++) {
        va[q] = *(const uint4*)(gA + (ks + 1) * 64 + q * 8);
        vb[q] = *(const uint4*)(gB + (ks + 1) * 64 + q * 8);
      }
    }
    f16x8 bfr[4][2];
#pragma unroll
    for (int nt = 0; nt < 4; nt++)
#pragma unroll
      for (int kk = 0; kk < 2; kk++) {
        const int row = wc * 64 + nt * 16 + ln16;
        const int byte = row * 128 + ((kk * 64 + g * 16) ^ ((row & 7) << 4));
        bfr[nt][kk] = *(const f16x8*)((const char*)Bt + byte);
      }
#pragma unroll
    for (int mt = 0; mt < 4; mt++) {
      f16x8 afr[2];
#pragma unroll
      for (int kk = 0; kk < 2; kk++) {
        const int row = wr * 64 + mt * 16 + ln16;
        const int byte = row * 128 + ((kk * 64 + g * 16) ^ ((row & 7) << 4));
        afr[kk] = *(const f16x8*)((const char*)At + byte);
      }
#pragma unroll
      for (int nt = 0; nt < 4; nt++) {
        acc[mt][nt] =
            __builtin_amdgcn_mfma_f32_16x16x32_f16(afr[0], bfr[nt][0], acc[mt][nt], 0, 0, 0);
        acc[mt][nt] =
            __builtin_amdgcn_mfma_f32_16x16x32_f16(afr[1], bfr[nt][1], acc[mt][nt], 0, 0, 0);
      }
    }
    __syncthreads();  // all reads done before LDS overwrite
    if (more) {
#pragma unroll
      for (int q = 0; q < 4; q++) {
        *(uint4*)((char*)At + swb[q]) = va[q];
        *(uint4*)((char*)Bt + swb[q]) = vb[q];
      }
      __syncthreads();
    }
  }

  // epilogue (round-11 form + nontemporal): stage 128x128 fp16 tile in LDS,
  // stream out 128B/thread with nt stores (no L2 allocation).
  f16* otile = smem;
#pragma unroll
  for (int mt = 0; mt < 4; mt++)
#pragma unroll
    for (int reg = 0; reg < 4; reg++) {
      const int il = wr * 64 + mt * 16 + g * 4 + reg;
#pragma unroll
      for (int nt = 0; nt < 4; nt++) {
        const int jl = wc * 64 + nt * 16 + ln16;
        const int byte = (il * 256 + jl * 2) ^ ((il & 7) << 4);
        *(f16*)((char*)otile + byte) = (f16)acc[mt][nt][reg];
      }
    }
  __syncthreads();
  {
    const int i = t >> 1, jh = t & 1;
    f16* __restrict__ dst =
        o16 + (size_t)c * NROW + (size_t)(i0 + i) * 512 + j0 + jh * 64;
#pragma unroll
    for (int e = 0; e < 8; e++) {
      const int byte = (i * 256 + jh * 128 + e * 16) ^ ((i & 7) << 4);
      const u32x4 v = *(const u32x4*)((const char*)otile + byte);
      __builtin_nontemporal_store(v, (u32x4*)(dst + e * 8));
    }
  }
}

// ------- pass 3a: on_t[r][c] = LN_c(o16[c][r])  (transpose via LDS) ---------
// UNCHANGED from round-11 build.
__global__ __launch_bounds__(256) void k_pass3a(
    const f16* __restrict__ o16,
    const float* __restrict__ lnwo, const float* __restrict__ lnbo,
    f16* __restrict__ on_t) {
  __shared__ __attribute__((aligned(16))) f16 ot[64 * CH];  // 16 KB
  const int t = threadIdx.x, lane = t & 63, w = t >> 6;
  const size_t r0 = (size_t)blockIdx.x * 64;

  {
    const int c = t >> 1, rh = t & 1;
    const f16* src = o16 + (size_t)c * NROW + r0 + rh * 32;
    u16x8 d[4];
#pragma unroll
    for (int q = 0; q < 4; q++) d[q] = *(const u16x8*)((const u16*)src + q * 8);
#pragma unroll
    for (int i = 0; i < 32; i++) {
      const int r = rh * 32 + i;
      const int byte = (r * 256 + c * 2) ^ ((r & 7) << 4);
      *(u16*)((char*)ot + byte) = d[i >> 3][i & 7];
    }
  }
  __syncthreads();

  {
    const int rr = lane >> 4, q = lane & 15;
    const float4 lw0 = *(const float4*)(lnwo + q * 8);
    const float4 lw1 = *(const float4*)(lnwo + q * 8 + 4);
    const float4 lb0 = *(const float4*)(lnbo + q * 8);
    const float4 lb1 = *(const float4*)(lnbo + q * 8 + 4);
    for (int it = 0; it < 4; it++) {
      const int row = w * 16 + it * 4 + rr;
      const int byte = (row * 256 + q * 16) ^ ((row & 7) << 4);
      const f16x8 v = *(const f16x8*)((const char*)ot + byte);
      float x[8];
#pragma unroll
      for (int e = 0; e < 8; e++) x[e] = (float)v[e];
      float s = 0.f, sq = 0.f;
#pragma unroll
      for (int e = 0; e < 8; e++) { s += x[e]; sq += x[e] * x[e]; }
#pragma unroll
      for (int off = 8; off > 0; off >>= 1) {
        s += __shfl_xor(s, off);
        sq += __shfl_xor(sq, off);
      }
      const float mu = s * (1.0f / 128.0f);
      const float rs = rsqrtf(sq * (1.0f / 128.0f) - mu * mu + 1e-5f);
      f16x8 p;
      p[0] = (f16)((x[0] - mu) * rs * lw0.x + lb0.x);
      p[1] = (f16)((x[1] - mu) * rs * lw0.y + lb0.y);
      p[2] = (f16)((x[2] - mu) * rs * lw0.z + lb0.z);
      p[3] = (f16)((x[3] - mu) * rs * lw0.w + lb0.w);
      p[4] = (f16)((x[4] - mu) * rs * lw1.x + lb1.x);
      p[5] = (f16)((x[5] - mu) * rs * lw1.y + lb1.y);
      p[6] = (f16)((x[6] - mu) * rs * lw1.z + lb1.z);
      p[7] = (f16)((x[7] - mu) * rs * lw1.w + lb1.w);
      *(f16x8*)(on_t + (r0 + row) * CH + q * 8) = p;
    }
  }
}

// ------- pass 3b: out = sigmoid(LN(z)@w_g^T) * (on @ w_o^T)  (MFMA fp16) ----
// UNCHANGED from round-11 build.
__global__ __launch_bounds__(256) void k_pass3b(
    const float* __restrict__ z,
    const float* __restrict__ lnwi, const float* __restrict__ lnbi,
    const f16* __restrict__ on_t,
    const f16* __restrict__ wq3,  // [w_g | w_o] fp16, 128x128 each
    float* __restrict__ out) {
  __shared__ __attribute__((aligned(16))) f16 zn[64 * CH];  // 16 KB
  __shared__ __attribute__((aligned(16))) f16 on[64 * CH];  // 16 KB
  const int t = threadIdx.x, lane = t & 63, w = t >> 6;
  const size_t r0 = (size_t)blockIdx.x * 64;

  {
    const int row = t >> 2, ch0 = (t & 3) * 32;
    const u16* src = (const u16*)(on_t + (r0 + row) * CH + ch0);
#pragma unroll
    for (int e = 0; e < 4; e++) {
      const uint4 v = *(const uint4*)(src + e * 8);
      const int byte = (row * 256 + (ch0 + e * 8) * 2) ^ ((row & 7) << 4);
      *(uint4*)((char*)on + byte) = v;
    }
  }
  {
    const int rr = lane >> 4, q = lane & 15;
    const float4 lw0 = *(const float4*)(lnwi + q * 8);
    const float4 lw1 = *(const float4*)(lnwi + q * 8 + 4);
    const float4 lb0 = *(const float4*)(lnbi + q * 8);
    const float4 lb1 = *(const float4*)(lnbi + q * 8 + 4);
    for (int it = 0; it < 4; it++) {
      const int row = w * 16 + it * 4 + rr;
      const float* src = z + (r0 + row) * CH + q * 8;
      const float4 v0 = *(const float4*)(src);
      const float4 v1 = *(const float4*)(src + 4);
      float s = v0.x + v0.y + v0.z + v0.w + v1.x + v1.y + v1.z + v1.w;
      float sq = v0.x * v0.x + v0.y * v0.y + v0.z * v0.z + v0.w * v0.w +
                 v1.x * v1.x + v1.y * v1.y + v1.z * v1.z + v1.w * v1.w;
#pragma unroll
      for (int off = 8; off > 0; off >>= 1) {
        s += __shfl_xor(s, off);
        sq += __shfl_xor(sq, off);
      }
      const float mu = s * (1.0f / 128.0f);
      const float rs = rsqrtf(sq * (1.0f / 128.0f) - mu * mu + 1e-5f);
      f16x8 p;
      p[0] = (f16)((v0.x - mu) * rs * lw0.x + lb0.x);
      p[1] = (f16)((v0.y - mu) * rs * lw0.y + lb0.y);
      p[2] = (f16)((v0.z - mu) * rs * lw0.z + lb0.z);
      p[3] = (f16)((v0.w - mu) * rs * lw0.w + lb0.w);
      p[4] = (f16)((v1.x - mu) * rs * lw1.x + lb1.x);
      p[5] = (f16)((v1.y - mu) * rs * lw1.y + lb1.y);
      p[6] = (f16)((v1.z - mu) * rs * lw1.z + lb1.z);
      p[7] = (f16)((v1.w - mu) * rs * lw1.w + lb1.w);
      const int byte = (row * 256 + q * 16) ^ ((row & 7) << 4);
      *(f16x8*)((char*)zn + byte) = p;
    }
  }
  __syncthreads();

  const int g = lane >> 4, ln16 = lane & 15;
  const f16* __restrict__ wg = wq3;
  const f16* __restrict__ wo = wq3 + (size_t)CH * CH;
#pragma unroll
  for (int f = 0; f < 2; f++) {
    const int col = w * 32 + f * 16 + ln16;
    f16x8 bg[4], bo[4];
#pragma unroll
    for (int ks = 0; ks < 4; ks++) {
      const size_t woff = (size_t)col * CH + ks * 32 + g * 8;
      bg[ks] = *(const f16x8*)(wg + woff);
      bo[ks] = *(const f16x8*)(wo + woff);
    }
#pragma unroll
    for (int mt = 0; mt < 4; mt++) {
      const int m0 = mt * 16;
      const int row = m0 + ln16;
      f32x4 accG = {0.f, 0.f, 0.f, 0.f}, accP = {0.f, 0.f, 0.f, 0.f};
#pragma unroll
      for (int ks = 0; ks < 4; ks++) {
        const int byte =
            (row * 256 + (ks * 32 + g * 8) * 2) ^ ((row & 7) << 4);
        const f16x8 az = *(const f16x8*)((const char*)zn + byte);
        const f16x8 ao = *(const f16x8*)((const char*)on + byte);
        accG = __builtin_amdgcn_mfma_f32_16x16x32_f16(az, bg[ks], accG, 0, 0, 0);
        accP = __builtin_amdgcn_mfma_f32_16x16x32_f16(ao, bo[ks], accP, 0, 0, 0);
      }
#pragma unroll
      for (int reg = 0; reg < 4; reg++) {
        const int orow = m0 + g * 4 + reg;
        out[(r0 + orow) * CH + col] = sigmoidf_(accG[reg]) * accP[reg];
      }
    }
  }
}

extern "C" void kernel_launch(void* const* d_in, const int* in_sizes, int n_in,
                              void* d_out, int out_size, void* d_ws, size_t ws_size,
                              hipStream_t stream) {
  const float* z = (const float*)d_in[0];
  const float* pm = (const float*)d_in[1];
  const float* ln_in_w = (const float*)d_in[2];
  const float* ln_in_b = (const float*)d_in[3];
  const float* ln_out_w = (const float*)d_in[4];
  const float* ln_out_b = (const float*)d_in[5];
  const float* w_pa = (const float*)d_in[6];
  const float* w_pb = (const float*)d_in[7];
  const float* w_ga = (const float*)d_in[8];
  const float* w_gb = (const float*)d_in[9];
  const float* w_g = (const float*)d_in[10];
  const float* w_o = (const float*)d_in[11];

  // ws: a_t | b_t (fp16, 64 MB each). After pass2: wq3 @ws start, on_t @+64MB.
  // d_out: wq (128KB) -> o16 fp16 c-major (64MB) -> final out (128MB fp32).
  f16* a_t = (f16*)d_ws;
  f16* b_t = a_t + (size_t)CH * NROW;
  float* out = (float*)d_out;
  f16* wq = (f16*)d_out;
  f16* o16 = (f16*)d_out;
  f16* wq3 = (f16*)d_ws;
  f16* on_t = b_t;

  k_pass0<<<256, 256, 0, stream>>>(w_pa, w_ga, w_pb, w_gb, wq);
  k_pass1<<<4096, 256, 0, stream>>>(z, pm, ln_in_w, ln_in_b, wq, a_t, b_t);
  k_pass2<<<2048, 256, 0, stream>>>(a_t, b_t, o16);
  k_cvt2<<<128, 256, 0, stream>>>(w_g, w_o, wq3);
  k_pass3a<<<4096, 256, 0, stream>>>(o16, ln_out_w, ln_out_b, on_t);
  k_pass3b<<<4096, 256, 0, stream>>>(z, ln_in_w, ln_in_b, on_t, wq3, out);
}

// Round 11
// 534.419 us; speedup vs baseline: 1.3553x; 1.3553x over previous
//
#include <hip/hip_runtime.h>
#include <hip/hip_fp16.h>

// TriangleMultiplicationOutgoing — MI355X (gfx950)
// ROUND 15: restructured pass2 + fused pass3. (pass0/cvt2/pass1 untouched.)
//   - pass2: block = (c, js): O_c[:, js*128..+128) = A_c(512x512) @ B_c[js]^T.
//     512 thr / 8 waves, BK=32, 40KB LDS. Output strip (128KB, contiguous)
//     written IN PLACE over b_t[c][js rows] — the exact rows only this block
//     reads (a_t read-only; (c,js') blocks disjoint) -> race-free, o16 lives
//     in ws. AI 1.5x r11; write region block-private contiguous.
//     Layout: o16s[c][js][i][jl] @ b_t + c*NROW + js*65536 + i*128 + jl.
//   - pass3 FUSED (3a+3b): transpose-gather o16s from ws -> LDS, in-place LN
//     (each (row,chunk) thread-owned), then verified MFMA gate+proj + stores.
//     Saves 128MB on_t round trip + one launch. No d_out read/write race:
//     o16s is in ws, out is d_out.
//   - d_out: wq (128KB, pass0->pass1) then final out only.

typedef unsigned short u16;
typedef unsigned int u32;
typedef unsigned short u16x8 __attribute__((ext_vector_type(8)));
typedef _Float16 f16;
typedef _Float16 f16x8 __attribute__((ext_vector_type(8)));
typedef _Float16 f16x2 __attribute__((ext_vector_type(2)));
typedef float f32x4 __attribute__((ext_vector_type(4)));

#define NROW 262144  // 512*512 spatial positions
#define CH 128

__device__ __forceinline__ float sigmoidf_(float x) {
  return 1.0f / (1.0f + __expf(-x));
}

// ---------------- pass 0: weights fp32 -> fp16, order [pa, ga, pb, gb] ------
__global__ __launch_bounds__(256) void k_pass0(
    const float* __restrict__ wpa, const float* __restrict__ wga,
    const float* __restrict__ wpb, const float* __restrict__ wgb,
    f16* __restrict__ wq) {
  const int m = blockIdx.x >> 6;
  const int idx = ((blockIdx.x & 63) << 8) + threadIdx.x;
  const float* src = (m == 0) ? wpa : (m == 1) ? wga : (m == 2) ? wpb : wgb;
  wq[(size_t)m * CH * CH + idx] = (f16)src[idx];
}

// ---------------- cvt2: w_g, w_o fp32 -> fp16 (into ws head) ----------------
__global__ __launch_bounds__(256) void k_cvt2(
    const float* __restrict__ w_g, const float* __restrict__ w_o,
    f16* __restrict__ wq3) {
  const int m = blockIdx.x >> 6;
  const int idx = ((blockIdx.x & 63) << 8) + threadIdx.x;
  const float* src = (m == 0) ? w_g : w_o;
  wq3[(size_t)m * CH * CH + idx] = (f16)src[idx];
}

// ---------------- pass 1: LN(z) + 4 projections -> a,b (fp16, [c][r]) -------
// UNCHANGED from verified round-9 build.
__global__ __launch_bounds__(256) void k_pass1(
    const float* __restrict__ z, const float* __restrict__ pm,
    const float* __restrict__ lnw, const float* __restrict__ lnb,
    const f16* __restrict__ wq,
    f16* __restrict__ a_t, f16* __restrict__ b_t) {
  __shared__ __attribute__((aligned(16))) f16 zn[64 * CH];  // 16 KB
  __shared__ __attribute__((aligned(16))) f16 ab[CH * 64];  // 16 KB (one pair)
  __shared__ float pmv[64];
  const int t = threadIdx.x, lane = t & 63, w = t >> 6;
  const size_t r0 = (size_t)blockIdx.x * 64;

  {
    const int rr = lane >> 4, q = lane & 15;
    const float4 lw0 = *(const float4*)(lnw + q * 8);
    const float4 lw1 = *(const float4*)(lnw + q * 8 + 4);
    const float4 lb0 = *(const float4*)(lnb + q * 8);
    const float4 lb1 = *(const float4*)(lnb + q * 8 + 4);
    for (int it = 0; it < 4; it++) {
      const int row = w * 16 + it * 4 + rr;
      const float* src = z + (r0 + row) * CH + q * 8;
      const float4 v0 = *(const float4*)(src);
      const float4 v1 = *(const float4*)(src + 4);
      float s = v0.x + v0.y + v0.z + v0.w + v1.x + v1.y + v1.z + v1.w;
      float sq = v0.x * v0.x + v0.y * v0.y + v0.z * v0.z + v0.w * v0.w +
                 v1.x * v1.x + v1.y * v1.y + v1.z * v1.z + v1.w * v1.w;
#pragma unroll
      for (int off = 8; off > 0; off >>= 1) {
        s += __shfl_xor(s, off);
        sq += __shfl_xor(sq, off);
      }
      const float mu = s * (1.0f / 128.0f);
      const float rs = rsqrtf(sq * (1.0f / 128.0f) - mu * mu + 1e-5f);
      f16x8 p;
      p[0] = (f16)((v0.x - mu) * rs * lw0.x + lb0.x);
      p[1] = (f16)((v0.y - mu) * rs * lw0.y + lb0.y);
      p[2] = (f16)((v0.z - mu) * rs * lw0.z + lb0.z);
      p[3] = (f16)((v0.w - mu) * rs * lw0.w + lb0.w);
      p[4] = (f16)((v1.x - mu) * rs * lw1.x + lb1.x);
      p[5] = (f16)((v1.y - mu) * rs * lw1.y + lb1.y);
      p[6] = (f16)((v1.z - mu) * rs * lw1.z + lb1.z);
      p[7] = (f16)((v1.w - mu) * rs * lw1.w + lb1.w);
      const int byte = (row * 256 + q * 16) ^ ((row & 7) << 4);
      *(f16x8*)((char*)zn + byte) = p;
      if (q == 0) pmv[row] = pm[r0 + row];
    }
  }
  __syncthreads();

  const int g = lane >> 4, ln16 = lane & 15;
#pragma unroll
  for (int pair = 0; pair < 2; pair++) {
    const f16* __restrict__ wp = wq + (size_t)(pair * 2 + 0) * CH * CH;
    const f16* __restrict__ wgp = wq + (size_t)(pair * 2 + 1) * CH * CH;
#pragma unroll
    for (int f = 0; f < 2; f++) {
      const int col = w * 32 + f * 16 + ln16;
      f16x8 bp[4], bg[4];
#pragma unroll
      for (int ks = 0; ks < 4; ks++) {
        const size_t wo = (size_t)col * CH + ks * 32 + g * 8;
        bp[ks] = *(const f16x8*)(wp + wo);
        bg[ks] = *(const f16x8*)(wgp + wo);
      }
#pragma unroll
      for (int mt = 0; mt < 4; mt++) {
        const int m0 = mt * 16;
        const int row = m0 + ln16;
        f32x4 accP = {0.f, 0.f, 0.f, 0.f}, accG = {0.f, 0.f, 0.f, 0.f};
#pragma unroll
        for (int ks = 0; ks < 4; ks++) {
          const int byte =
              (row * 256 + (ks * 32 + g * 8) * 2) ^ ((row & 7) << 4);
          const f16x8 af = *(const f16x8*)((const char*)zn + byte);
          accP = __builtin_amdgcn_mfma_f32_16x16x32_f16(af, bp[ks], accP, 0, 0, 0);
          accG = __builtin_amdgcn_mfma_f32_16x16x32_f16(af, bg[ks], accG, 0, 0, 0);
        }
        uint2 pk;
        {
          const int rbase = m0 + g * 4;
          const float v0 = pmv[rbase + 0] * sigmoidf_(accG[0]) * accP[0];
          const float v1 = pmv[rbase + 1] * sigmoidf_(accG[1]) * accP[1];
          const float v2 = pmv[rbase + 2] * sigmoidf_(accG[2]) * accP[2];
          const float v3 = pmv[rbase + 3] * sigmoidf_(accG[3]) * accP[3];
          f16x2 h01, h23;
          h01.x = (f16)v0; h01.y = (f16)v1;
          h23.x = (f16)v2; h23.y = (f16)v3;
          pk.x = *(u32*)&h01;
          pk.y = *(u32*)&h23;
        }
        const int byte = ((col * 64 + m0 + g * 4) * 2) ^ ((col & 7) << 4);
        *(uint2*)((char*)ab + byte) = pk;
      }
    }
    __syncthreads();
    {
      const int o = t >> 1, h = t & 1;
      f16* __restrict__ dst =
          (pair ? b_t : a_t) + (size_t)o * NROW + r0 + h * 32;
#pragma unroll
      for (int e = 0; e < 4; e++) {
        const int byte = ((o * 64 + h * 32 + e * 8) * 2) ^ ((o & 7) << 4);
        *(uint4*)(dst + e * 8) = *(const uint4*)((const char*)ab + byte);
      }
    }
    if (pair == 0) __syncthreads();
  }
}

// ------- pass 2: per (c, js): O strip = A_c @ B_c[js]^T, in place on b_t ----
// 512 threads / 8 waves; wave w owns i-rows [w*64, w*64+64), all 128 j.
// BK=32, 16 K-steps. Output o16s[c][js][i][jl] over b_t[c][js*128..+127][*].
__global__ __launch_bounds__(512, 1) void k_pass2(
    const f16* __restrict__ a_t, f16* bt) {
  __shared__ __attribute__((aligned(16))) f16 At[512 * 32];  // 32 KB
  __shared__ __attribute__((aligned(16))) f16 Bt[128 * 32];  // 8 KB
  const int t = threadIdx.x, lane = t & 63, w = t >> 6;
  const int bx = blockIdx.x;
  const int xcd = bx & 7, s = bx >> 3;
  const int c = xcd + ((s >> 2) << 3);  // 0..127
  const int js = s & 3;
  const int g = lane >> 4, ln16 = lane & 15;

  // staging addresses
  const f16* gA = a_t + (size_t)c * NROW + (size_t)t * 512;          // row t
  const f16* gB = bt + (size_t)c * NROW +
                  (size_t)(js * 128 + (t >> 2)) * 512 + (t & 3) * 8;  // 16B
  const int aRow = t, bRow = t >> 2, bChunk = t & 3;

  f32x4 acc[4][8];
#pragma unroll
  for (int mt = 0; mt < 4; mt++)
#pragma unroll
    for (int nt = 0; nt < 8; nt++) acc[mt][nt] = {0.f, 0.f, 0.f, 0.f};

  // prologue: stage K-step 0
  uint4 va[4];
  uint4 vb;
#pragma unroll
  for (int q = 0; q < 4; q++) va[q] = *(const uint4*)(gA + q * 8);
  vb = *(const uint4*)(gB);
#pragma unroll
  for (int q = 0; q < 4; q++)
    *(uint4*)((char*)At + aRow * 64 + ((q * 16) ^ ((aRow & 3) << 4))) = va[q];
  *(uint4*)((char*)Bt + bRow * 64 + ((bChunk * 16) ^ ((bRow & 3) << 4))) = vb;
  __syncthreads();

  for (int ks = 0; ks < 16; ks++) {
    const bool more = (ks + 1) < 16;
    if (more) {  // T14: issue next K-step loads early
#pragma unroll
      for (int q = 0; q < 4; q++)
        va[q] = *(const uint4*)(gA + (ks + 1) * 32 + q * 8);
      vb = *(const uint4*)(gB + (ks + 1) * 32);
    }
    f16x8 bfr[8];
#pragma unroll
    for (int nt = 0; nt < 8; nt++) {
      const int row = nt * 16 + ln16;
      bfr[nt] = *(const f16x8*)((const char*)Bt + row * 64 +
                                ((g * 16) ^ ((row & 3) << 4)));
    }
#pragma unroll
    for (int mt = 0; mt < 4; mt++) {
      const int row = w * 64 + mt * 16 + ln16;
      const f16x8 afr = *(const f16x8*)((const char*)At + row * 64 +
                                        ((g * 16) ^ ((row & 3) << 4)));
#pragma unroll
      for (int nt = 0; nt < 8; nt++)
        acc[mt][nt] =
            __builtin_amdgcn_mfma_f32_16x16x32_f16(afr, bfr[nt], acc[mt][nt], 0, 0, 0);
    }
    __syncthreads();  // readers done before overwrite
    if (more) {
#pragma unroll
      for (int q = 0; q < 4; q++)
        *(uint4*)((char*)At + aRow * 64 + ((q * 16) ^ ((aRow & 3) << 4))) = va[q];
      *(uint4*)((char*)Bt + bRow * 64 + ((bChunk * 16) ^ ((bRow & 3) << 4))) = vb;
      __syncthreads();
    }
  }
  __syncthreads();  // all At/Bt reads complete before epilogue reuse

  // epilogue: per-wave 4KB bounce region in At; 4 rounds of 16 i-rows.
  char* lbase = (char*)At + w * 4096;
  f16* dstBase = bt + (size_t)c * NROW + (size_t)js * 65536;
#pragma unroll
  for (int mt = 0; mt < 4; mt++) {
#pragma unroll
    for (int nt = 0; nt < 8; nt++)
#pragma unroll
      for (int reg = 0; reg < 4; reg++) {
        const int il = g * 4 + reg;           // 0..15
        const int jj = nt * 16 + ln16;        // 0..127
        const int byte = (il * 256 + jj * 2) ^ ((il & 7) << 4);
        *(f16*)(lbase + byte) = (f16)acc[mt][nt][reg];
      }
    __syncthreads();
    {
      const int il2 = lane >> 2, ch = lane & 3;
      f16* dst = dstBase + (size_t)(w * 64 + mt * 16 + il2) * 128 + ch * 32;
#pragma unroll
      for (int e = 0; e < 4; e++) {
        const int byte = (il2 * 256 + ch * 64 + e * 16) ^ ((il2 & 7) << 4);
        *(uint4*)(dst + e * 8) = *(const uint4*)(lbase + byte);
      }
    }
    __syncthreads();
  }
}

// ------- pass 3 (FUSED): out = sigmoid(LN(z)@w_g^T) * (LN_c(o) @ w_o^T) -----
// Reads o16s[c][js][i][jl] from ws; transpose-gather -> LDS, in-place LN,
// then verified MFMA phase. Writes out (d_out) — no aliasing with o16s.
__global__ __launch_bounds__(256) void k_pass3(
    const float* __restrict__ z,
    const float* __restrict__ lnwi, const float* __restrict__ lnbi,
    const float* __restrict__ lnwo, const float* __restrict__ lnbo,
    const f16* __restrict__ o16s,
    const f16* __restrict__ wq3,  // [w_g | w_o] fp16, 128x128 each
    float* __restrict__ out) {
  __shared__ __attribute__((aligned(16))) f16 zn[64 * CH];  // 16 KB
  __shared__ __attribute__((aligned(16))) f16 on[64 * CH];  // 16 KB
  const int t = threadIdx.x, lane = t & 63, w = t >> 6;
  const size_t r0 = (size_t)blockIdx.x * 64;
  const int i = (int)(r0 >> 9);        // spatial row (fixed per block)
  const int j0 = (int)(r0 & 511);      // 64-aligned
  const int js = j0 >> 7, jl0 = j0 & 127;

  // Phase A0: transpose-gather o16s -> on (swizzled). thread: c=t>>1, h=t&1.
  {
    const int c = t >> 1, h = t & 1;
    const f16* src = o16s + (size_t)c * NROW + (size_t)js * 65536 +
                     (size_t)i * 128 + jl0 + h * 32;
    u16x8 d[4];
#pragma unroll
    for (int q = 0; q < 4; q++) d[q] = *(const u16x8*)((const u16*)src + q * 8);
#pragma unroll
    for (int idx = 0; idx < 32; idx++) {
      const int rloc = h * 32 + idx;
      const int byte = (rloc * 256 + c * 2) ^ ((rloc & 7) << 4);
      *(u16*)((char*)on + byte) = d[idx >> 3][idx & 7];
    }
  }
  // Phase A1: LN(z) -> zn (verified shape).
  {
    const int rr = lane >> 4, q = lane & 15;
    const float4 lw0 = *(const float4*)(lnwi + q * 8);
    const float4 lw1 = *(const float4*)(lnwi + q * 8 + 4);
    const float4 lb0 = *(const float4*)(lnbi + q * 8);
    const float4 lb1 = *(const float4*)(lnbi + q * 8 + 4);
    for (int it = 0; it < 4; it++) {
      const int row = w * 16 + it * 4 + rr;
      const float* src = z + (r0 + row) * CH + q * 8;
      const float4 v0 = *(const float4*)(src);
      const float4 v1 = *(const float4*)(src + 4);
      float s = v0.x + v0.y + v0.z + v0.w + v1.x + v1.y + v1.z + v1.w;
      float sq = v0.x * v0.x + v0.y * v0.y + v0.z * v0.z + v0.w * v0.w +
                 v1.x * v1.x + v1.y * v1.y + v1.z * v1.z + v1.w * v1.w;
#pragma unroll
      for (int off = 8; off > 0; off >>= 1) {
        s += __shfl_xor(s, off);
        sq += __shfl_xor(sq, off);
      }
      const float mu = s * (1.0f / 128.0f);
      const float rs = rsqrtf(sq * (1.0f / 128.0f) - mu * mu + 1e-5f);
      f16x8 p;
      p[0] = (f16)((v0.x - mu) * rs * lw0.x + lb0.x);
      p[1] = (f16)((v0.y - mu) * rs * lw0.y + lb0.y);
      p[2] = (f16)((v0.z - mu) * rs * lw0.z + lb0.z);
      p[3] = (f16)((v0.w - mu) * rs * lw0.w + lb0.w);
      p[4] = (f16)((v1.x - mu) * rs * lw1.x + lb1.x);
      p[5] = (f16)((v1.y - mu) * rs * lw1.y + lb1.y);
      p[6] = (f16)((v1.z - mu) * rs * lw1.z + lb1.z);
      p[7] = (f16)((v1.w - mu) * rs * lw1.w + lb1.w);
      const int byte = (row * 256 + q * 16) ^ ((row & 7) << 4);
      *(f16x8*)((char*)zn + byte) = p;
    }
  }
  __syncthreads();

  // Phase B: in-place LN over 'on' (each (row,16B-chunk) thread-owned).
  {
    const int rr = lane >> 4, q = lane & 15;
    const float4 lw0 = *(const float4*)(lnwo + q * 8);
    const float4 lw1 = *(const float4*)(lnwo + q * 8 + 4);
    const float4 lb0 = *(const float4*)(lnbo + q * 8);
    const float4 lb1 = *(const float4*)(lnbo + q * 8 + 4);
    for (int it = 0; it < 4; it++) {
      const int row = w * 16 + it * 4 + rr;
      const int byte = (row * 256 + q * 16) ^ ((row & 7) << 4);
      const f16x8 v = *(const f16x8*)((const char*)on + byte);
      float x[8];
#pragma unroll
      for (int e = 0; e < 8; e++) x[e] = (float)v[e];
      float s = 0.f, sq = 0.f;
#pragma unroll
      for (int e = 0; e < 8; e++) { s += x[e]; sq += x[e] * x[e]; }
#pragma unroll
      for (int off = 8; off > 0; off >>= 1) {
        s += __shfl_xor(s, off);
        sq += __shfl_xor(sq, off);
      }
      const float mu = s * (1.0f / 128.0f);
      const float rs = rsqrtf(sq * (1.0f / 128.0f) - mu * mu + 1e-5f);
      f16x8 p;
      p[0] = (f16)((x[0] - mu) * rs * lw0.x + lb0.x);
      p[1] = (f16)((x[1] - mu) * rs * lw0.y + lb0.y);
      p[2] = (f16)((x[2] - mu) * rs * lw0.z + lb0.z);
      p[3] = (f16)((x[3] - mu) * rs * lw0.w + lb0.w);
      p[4] = (f16)((x[4] - mu) * rs * lw1.x + lb1.x);
      p[5] = (f16)((x[5] - mu) * rs * lw1.y + lb1.y);
      p[6] = (f16)((x[6] - mu) * rs * lw1.z + lb1.z);
      p[7] = (f16)((x[7] - mu) * rs * lw1.w + lb1.w);
      *(f16x8*)((char*)on + byte) = p;
    }
  }
  __syncthreads();

  // Phase C: MFMA gate+proj with per-f hoisted weights; direct stores.
  const int g = lane >> 4, ln16 = lane & 15;
  const f16* __restrict__ wg = wq3;
  const f16* __restrict__ wo = wq3 + (size_t)CH * CH;
#pragma unroll
  for (int f = 0; f < 2; f++) {
    const int col = w * 32 + f * 16 + ln16;
    f16x8 bg[4], bo[4];
#pragma unroll
    for (int ks = 0; ks < 4; ks++) {
      const size_t woff = (size_t)col * CH + ks * 32 + g * 8;
      bg[ks] = *(const f16x8*)(wg + woff);
      bo[ks] = *(const f16x8*)(wo + woff);
    }
#pragma unroll
    for (int mt = 0; mt < 4; mt++) {
      const int m0 = mt * 16;
      const int row = m0 + ln16;
      f32x4 accG = {0.f, 0.f, 0.f, 0.f}, accP = {0.f, 0.f, 0.f, 0.f};
#pragma unroll
      for (int ks = 0; ks < 4; ks++) {
        const int byte =
            (row * 256 + (ks * 32 + g * 8) * 2) ^ ((row & 7) << 4);
        const f16x8 az = *(const f16x8*)((const char*)zn + byte);
        const f16x8 ao = *(const f16x8*)((const char*)on + byte);
        accG = __builtin_amdgcn_mfma_f32_16x16x32_f16(az, bg[ks], accG, 0, 0, 0);
        accP = __builtin_amdgcn_mfma_f32_16x16x32_f16(ao, bo[ks], accP, 0, 0, 0);
      }
#pragma unroll
      for (int reg = 0; reg < 4; reg++) {
        const int orow = m0 + g * 4 + reg;
        out[(r0 + orow) * CH + col] = sigmoidf_(accG[reg]) * accP[reg];
      }
    }
  }
}

extern "C" void kernel_launch(void* const* d_in, const int* in_sizes, int n_in,
                              void* d_out, int out_size, void* d_ws, size_t ws_size,
                              hipStream_t stream) {
  const float* z = (const float*)d_in[0];
  const float* pm = (const float*)d_in[1];
  const float* ln_in_w = (const float*)d_in[2];
  const float* ln_in_b = (const float*)d_in[3];
  const float* ln_out_w = (const float*)d_in[4];
  const float* ln_out_b = (const float*)d_in[5];
  const float* w_pa = (const float*)d_in[6];
  const float* w_pb = (const float*)d_in[7];
  const float* w_ga = (const float*)d_in[8];
  const float* w_gb = (const float*)d_in[9];
  const float* w_g = (const float*)d_in[10];
  const float* w_o = (const float*)d_in[11];

  // ws: a_t [0,64MB) | b_t [64,128MB). pass2 overwrites b_t with o16s in
  // place (strip-ownership safe). After pass2: wq3 (64KB) at a_t head.
  // d_out: wq (128KB, pass0->pass1) -> final out (128MB, fused pass3).
  f16* a_t = (f16*)d_ws;
  f16* b_t = a_t + (size_t)CH * NROW;
  float* out = (float*)d_out;
  f16* wq = (f16*)d_out;
  f16* wq3 = (f16*)d_ws;

  k_pass0<<<256, 256, 0, stream>>>(w_pa, w_ga, w_pb, w_gb, wq);
  k_pass1<<<4096, 256, 0, stream>>>(z, pm, ln_in_w, ln_in_b, wq, a_t, b_t);
  k_pass2<<<512, 512, 0, stream>>>(a_t, b_t);
  k_cvt2<<<128, 256, 0, stream>>>(w_g, w_o, wq3);
  k_pass3<<<4096, 256, 0, stream>>>(z, ln_in_w, ln_in_b, ln_out_w, ln_out_b,
                                    b_t, wq3, out);
}

// Round 12
// 533.211 us; speedup vs baseline: 1.3584x; 1.0023x over previous
//
#include <hip/hip_runtime.h>
#include <hip/hip_fp16.h>

// TriangleMultiplicationOutgoing — MI355X (gfx950)
// ROUND 16: pass1 occupancy fix ONLY (everything else = verified round 15).
//   Evidence: LDS_Block_Size 33280 (zn16K+ab16K+pmv512) -> 4.92 -> 4 blk/CU.
//   Fix: pmv moves to registers (pm[r0+lane] coalesced + 16 one-time shfls)
//   -> LDS exactly 32768 -> 5 blk/CU (20 waves, +25%). launch_bounds(256,5)
//   caps VGPR at 102 (have ~73). LN row-loop unrolled for ILP.

typedef unsigned short u16;
typedef unsigned int u32;
typedef unsigned short u16x8 __attribute__((ext_vector_type(8)));
typedef _Float16 f16;
typedef _Float16 f16x8 __attribute__((ext_vector_type(8)));
typedef _Float16 f16x2 __attribute__((ext_vector_type(2)));
typedef float f32x4 __attribute__((ext_vector_type(4)));

#define NROW 262144  // 512*512 spatial positions
#define CH 128

__device__ __forceinline__ float sigmoidf_(float x) {
  return 1.0f / (1.0f + __expf(-x));
}

// ---------------- pass 0: weights fp32 -> fp16, order [pa, ga, pb, gb] ------
__global__ __launch_bounds__(256) void k_pass0(
    const float* __restrict__ wpa, const float* __restrict__ wga,
    const float* __restrict__ wpb, const float* __restrict__ wgb,
    f16* __restrict__ wq) {
  const int m = blockIdx.x >> 6;
  const int idx = ((blockIdx.x & 63) << 8) + threadIdx.x;
  const float* src = (m == 0) ? wpa : (m == 1) ? wga : (m == 2) ? wpb : wgb;
  wq[(size_t)m * CH * CH + idx] = (f16)src[idx];
}

// ---------------- cvt2: w_g, w_o fp32 -> fp16 (into ws head) ----------------
__global__ __launch_bounds__(256) void k_cvt2(
    const float* __restrict__ w_g, const float* __restrict__ w_o,
    f16* __restrict__ wq3) {
  const int m = blockIdx.x >> 6;
  const int idx = ((blockIdx.x & 63) << 8) + threadIdx.x;
  const float* src = (m == 0) ? w_g : w_o;
  wq3[(size_t)m * CH * CH + idx] = (f16)src[idx];
}

// ---------------- pass 1: LN(z) + 4 projections -> a,b (fp16, [c][r]) -------
// 64 rows/block, 4096 blocks, 4 waves. LDS exactly 32KB -> 5 blocks/CU.
__global__ __launch_bounds__(256, 5) void k_pass1(
    const float* __restrict__ z, const float* __restrict__ pm,
    const float* __restrict__ lnw, const float* __restrict__ lnb,
    const f16* __restrict__ wq,
    f16* __restrict__ a_t, f16* __restrict__ b_t) {
  __shared__ __attribute__((aligned(16))) f16 zn[64 * CH];  // 16 KB
  __shared__ __attribute__((aligned(16))) f16 ab[CH * 64];  // 16 KB (one pair)
  const int t = threadIdx.x, lane = t & 63, w = t >> 6;
  const size_t r0 = (size_t)blockIdx.x * 64;

  // mask row values: one coalesced load per wave; epilogue rows via shfl.
  const float pv = pm[r0 + lane];

  {
    const int rr = lane >> 4, q = lane & 15;
    const float4 lw0 = *(const float4*)(lnw + q * 8);
    const float4 lw1 = *(const float4*)(lnw + q * 8 + 4);
    const float4 lb0 = *(const float4*)(lnb + q * 8);
    const float4 lb1 = *(const float4*)(lnb + q * 8 + 4);
#pragma unroll
    for (int it = 0; it < 4; it++) {
      const int row = w * 16 + it * 4 + rr;
      const float* src = z + (r0 + row) * CH + q * 8;
      const float4 v0 = *(const float4*)(src);
      const float4 v1 = *(const float4*)(src + 4);
      float s = v0.x + v0.y + v0.z + v0.w + v1.x + v1.y + v1.z + v1.w;
      float sq = v0.x * v0.x + v0.y * v0.y + v0.z * v0.z + v0.w * v0.w +
                 v1.x * v1.x + v1.y * v1.y + v1.z * v1.z + v1.w * v1.w;
#pragma unroll
      for (int off = 8; off > 0; off >>= 1) {
        s += __shfl_xor(s, off);
        sq += __shfl_xor(sq, off);
      }
      const float mu = s * (1.0f / 128.0f);
      const float rs = rsqrtf(sq * (1.0f / 128.0f) - mu * mu + 1e-5f);
      f16x8 p;
      p[0] = (f16)((v0.x - mu) * rs * lw0.x + lb0.x);
      p[1] = (f16)((v0.y - mu) * rs * lw0.y + lb0.y);
      p[2] = (f16)((v0.z - mu) * rs * lw0.z + lb0.z);
      p[3] = (f16)((v0.w - mu) * rs * lw0.w + lb0.w);
      p[4] = (f16)((v1.x - mu) * rs * lw1.x + lb1.x);
      p[5] = (f16)((v1.y - mu) * rs * lw1.y + lb1.y);
      p[6] = (f16)((v1.z - mu) * rs * lw1.z + lb1.z);
      p[7] = (f16)((v1.w - mu) * rs * lw1.w + lb1.w);
      const int byte = (row * 256 + q * 16) ^ ((row & 7) << 4);
      *(f16x8*)((char*)zn + byte) = p;
    }
  }
  __syncthreads();

  const int g = lane >> 4, ln16 = lane & 15;
  // per-thread mask values for epilogue rows mt*16 + g*4 + reg
  float mv[16];
#pragma unroll
  for (int mt = 0; mt < 4; mt++)
#pragma unroll
    for (int reg = 0; reg < 4; reg++)
      mv[mt * 4 + reg] = __shfl(pv, mt * 16 + g * 4 + reg);

#pragma unroll
  for (int pair = 0; pair < 2; pair++) {
    const f16* __restrict__ wp = wq + (size_t)(pair * 2 + 0) * CH * CH;
    const f16* __restrict__ wgp = wq + (size_t)(pair * 2 + 1) * CH * CH;
#pragma unroll
    for (int f = 0; f < 2; f++) {
      const int col = w * 32 + f * 16 + ln16;
      f16x8 bp[4], bg[4];
#pragma unroll
      for (int ks = 0; ks < 4; ks++) {
        const size_t wo = (size_t)col * CH + ks * 32 + g * 8;
        bp[ks] = *(const f16x8*)(wp + wo);
        bg[ks] = *(const f16x8*)(wgp + wo);
      }
#pragma unroll
      for (int mt = 0; mt < 4; mt++) {
        const int m0 = mt * 16;
        const int row = m0 + ln16;
        f32x4 accP = {0.f, 0.f, 0.f, 0.f}, accG = {0.f, 0.f, 0.f, 0.f};
#pragma unroll
        for (int ks = 0; ks < 4; ks++) {
          const int byte =
              (row * 256 + (ks * 32 + g * 8) * 2) ^ ((row & 7) << 4);
          const f16x8 af = *(const f16x8*)((const char*)zn + byte);
          accP = __builtin_amdgcn_mfma_f32_16x16x32_f16(af, bp[ks], accP, 0, 0, 0);
          accG = __builtin_amdgcn_mfma_f32_16x16x32_f16(af, bg[ks], accG, 0, 0, 0);
        }
        uint2 pk;
        {
          const float v0 = mv[mt * 4 + 0] * sigmoidf_(accG[0]) * accP[0];
          const float v1 = mv[mt * 4 + 1] * sigmoidf_(accG[1]) * accP[1];
          const float v2 = mv[mt * 4 + 2] * sigmoidf_(accG[2]) * accP[2];
          const float v3 = mv[mt * 4 + 3] * sigmoidf_(accG[3]) * accP[3];
          f16x2 h01, h23;
          h01.x = (f16)v0; h01.y = (f16)v1;
          h23.x = (f16)v2; h23.y = (f16)v3;
          pk.x = *(u32*)&h01;
          pk.y = *(u32*)&h23;
        }
        const int byte = ((col * 64 + m0 + g * 4) * 2) ^ ((col & 7) << 4);
        *(uint2*)((char*)ab + byte) = pk;
      }
    }
    __syncthreads();
    {
      const int o = t >> 1, h = t & 1;
      f16* __restrict__ dst =
          (pair ? b_t : a_t) + (size_t)o * NROW + r0 + h * 32;
#pragma unroll
      for (int e = 0; e < 4; e++) {
        const int byte = ((o * 64 + h * 32 + e * 8) * 2) ^ ((o & 7) << 4);
        *(uint4*)(dst + e * 8) = *(const uint4*)((const char*)ab + byte);
      }
    }
    if (pair == 0) __syncthreads();
  }
}

// ------- pass 2: per (c, js): O strip = A_c @ B_c[js]^T, in place on b_t ----
// UNCHANGED from verified round-15 build.
__global__ __launch_bounds__(512, 1) void k_pass2(
    const f16* __restrict__ a_t, f16* bt) {
  __shared__ __attribute__((aligned(16))) f16 At[512 * 32];  // 32 KB
  __shared__ __attribute__((aligned(16))) f16 Bt[128 * 32];  // 8 KB
  const int t = threadIdx.x, lane = t & 63, w = t >> 6;
  const int bx = blockIdx.x;
  const int xcd = bx & 7, s = bx >> 3;
  const int c = xcd + ((s >> 2) << 3);  // 0..127
  const int js = s & 3;
  const int g = lane >> 4, ln16 = lane & 15;

  const f16* gA = a_t + (size_t)c * NROW + (size_t)t * 512;          // row t
  const f16* gB = bt + (size_t)c * NROW +
                  (size_t)(js * 128 + (t >> 2)) * 512 + (t & 3) * 8;  // 16B
  const int aRow = t, bRow = t >> 2, bChunk = t & 3;

  f32x4 acc[4][8];
#pragma unroll
  for (int mt = 0; mt < 4; mt++)
#pragma unroll
    for (int nt = 0; nt < 8; nt++) acc[mt][nt] = {0.f, 0.f, 0.f, 0.f};

  uint4 va[4];
  uint4 vb;
#pragma unroll
  for (int q = 0; q < 4; q++) va[q] = *(const uint4*)(gA + q * 8);
  vb = *(const uint4*)(gB);
#pragma unroll
  for (int q = 0; q < 4; q++)
    *(uint4*)((char*)At + aRow * 64 + ((q * 16) ^ ((aRow & 3) << 4))) = va[q];
  *(uint4*)((char*)Bt + bRow * 64 + ((bChunk * 16) ^ ((bRow & 3) << 4))) = vb;
  __syncthreads();

  for (int ks = 0; ks < 16; ks++) {
    const bool more = (ks + 1) < 16;
    if (more) {
#pragma unroll
      for (int q = 0; q < 4; q++)
        va[q] = *(const uint4*)(gA + (ks + 1) * 32 + q * 8);
      vb = *(const uint4*)(gB + (ks + 1) * 32);
    }
    f16x8 bfr[8];
#pragma unroll
    for (int nt = 0; nt < 8; nt++) {
      const int row = nt * 16 + ln16;
      bfr[nt] = *(const f16x8*)((const char*)Bt + row * 64 +
                                ((g * 16) ^ ((row & 3) << 4)));
    }
#pragma unroll
    for (int mt = 0; mt < 4; mt++) {
      const int row = w * 64 + mt * 16 + ln16;
      const f16x8 afr = *(const f16x8*)((const char*)At + row * 64 +
                                        ((g * 16) ^ ((row & 3) << 4)));
#pragma unroll
      for (int nt = 0; nt < 8; nt++)
        acc[mt][nt] =
            __builtin_amdgcn_mfma_f32_16x16x32_f16(afr, bfr[nt], acc[mt][nt], 0, 0, 0);
    }
    __syncthreads();
    if (more) {
#pragma unroll
      for (int q = 0; q < 4; q++)
        *(uint4*)((char*)At + aRow * 64 + ((q * 16) ^ ((aRow & 3) << 4))) = va[q];
      *(uint4*)((char*)Bt + bRow * 64 + ((bChunk * 16) ^ ((bRow & 3) << 4))) = vb;
      __syncthreads();
    }
  }
  __syncthreads();

  char* lbase = (char*)At + w * 4096;
  f16* dstBase = bt + (size_t)c * NROW + (size_t)js * 65536;
#pragma unroll
  for (int mt = 0; mt < 4; mt++) {
#pragma unroll
    for (int nt = 0; nt < 8; nt++)
#pragma unroll
      for (int reg = 0; reg < 4; reg++) {
        const int il = g * 4 + reg;
        const int jj = nt * 16 + ln16;
        const int byte = (il * 256 + jj * 2) ^ ((il & 7) << 4);
        *(f16*)(lbase + byte) = (f16)acc[mt][nt][reg];
      }
    __syncthreads();
    {
      const int il2 = lane >> 2, ch = lane & 3;
      f16* dst = dstBase + (size_t)(w * 64 + mt * 16 + il2) * 128 + ch * 32;
#pragma unroll
      for (int e = 0; e < 4; e++) {
        const int byte = (il2 * 256 + ch * 64 + e * 16) ^ ((il2 & 7) << 4);
        *(uint4*)(dst + e * 8) = *(const uint4*)(lbase + byte);
      }
    }
    __syncthreads();
  }
}

// ------- pass 3 (FUSED): out = sigmoid(LN(z)@w_g^T) * (LN_c(o) @ w_o^T) -----
// UNCHANGED from verified round-15 build.
__global__ __launch_bounds__(256) void k_pass3(
    const float* __restrict__ z,
    const float* __restrict__ lnwi, const float* __restrict__ lnbi,
    const float* __restrict__ lnwo, const float* __restrict__ lnbo,
    const f16* __restrict__ o16s,
    const f16* __restrict__ wq3,  // [w_g | w_o] fp16, 128x128 each
    float* __restrict__ out) {
  __shared__ __attribute__((aligned(16))) f16 zn[64 * CH];  // 16 KB
  __shared__ __attribute__((aligned(16))) f16 on[64 * CH];  // 16 KB
  const int t = threadIdx.x, lane = t & 63, w = t >> 6;
  const size_t r0 = (size_t)blockIdx.x * 64;
  const int i = (int)(r0 >> 9);
  const int j0 = (int)(r0 & 511);
  const int js = j0 >> 7, jl0 = j0 & 127;

  {
    const int c = t >> 1, h = t & 1;
    const f16* src = o16s + (size_t)c * NROW + (size_t)js * 65536 +
                     (size_t)i * 128 + jl0 + h * 32;
    u16x8 d[4];
#pragma unroll
    for (int q = 0; q < 4; q++) d[q] = *(const u16x8*)((const u16*)src + q * 8);
#pragma unroll
    for (int idx = 0; idx < 32; idx++) {
      const int rloc = h * 32 + idx;
      const int byte = (rloc * 256 + c * 2) ^ ((rloc & 7) << 4);
      *(u16*)((char*)on + byte) = d[idx >> 3][idx & 7];
    }
  }
  {
    const int rr = lane >> 4, q = lane & 15;
    const float4 lw0 = *(const float4*)(lnwi + q * 8);
    const float4 lw1 = *(const float4*)(lnwi + q * 8 + 4);
    const float4 lb0 = *(const float4*)(lnbi + q * 8);
    const float4 lb1 = *(const float4*)(lnbi + q * 8 + 4);
    for (int it = 0; it < 4; it++) {
      const int row = w * 16 + it * 4 + rr;
      const float* src = z + (r0 + row) * CH + q * 8;
      const float4 v0 = *(const float4*)(src);
      const float4 v1 = *(const float4*)(src + 4);
      float s = v0.x + v0.y + v0.z + v0.w + v1.x + v1.y + v1.z + v1.w;
      float sq = v0.x * v0.x + v0.y * v0.y + v0.z * v0.z + v0.w * v0.w +
                 v1.x * v1.x + v1.y * v1.y + v1.z * v1.z + v1.w * v1.w;
#pragma unroll
      for (int off = 8; off > 0; off >>= 1) {
        s += __shfl_xor(s, off);
        sq += __shfl_xor(sq, off);
      }
      const float mu = s * (1.0f / 128.0f);
      const float rs = rsqrtf(sq * (1.0f / 128.0f) - mu * mu + 1e-5f);
      f16x8 p;
      p[0] = (f16)((v0.x - mu) * rs * lw0.x + lb0.x);
      p[1] = (f16)((v0.y - mu) * rs * lw0.y + lb0.y);
      p[2] = (f16)((v0.z - mu) * rs * lw0.z + lb0.z);
      p[3] = (f16)((v0.w - mu) * rs * lw0.w + lb0.w);
      p[4] = (f16)((v1.x - mu) * rs * lw1.x + lb1.x);
      p[5] = (f16)((v1.y - mu) * rs * lw1.y + lb1.y);
      p[6] = (f16)((v1.z - mu) * rs * lw1.z + lb1.z);
      p[7] = (f16)((v1.w - mu) * rs * lw1.w + lb1.w);
      const int byte = (row * 256 + q * 16) ^ ((row & 7) << 4);
      *(f16x8*)((char*)zn + byte) = p;
    }
  }
  __syncthreads();

  {
    const int rr = lane >> 4, q = lane & 15;
    const float4 lw0 = *(const float4*)(lnwo + q * 8);
    const float4 lw1 = *(const float4*)(lnwo + q * 8 + 4);
    const float4 lb0 = *(const float4*)(lnbo + q * 8);
    const float4 lb1 = *(const float4*)(lnbo + q * 8 + 4);
    for (int it = 0; it < 4; it++) {
      const int row = w * 16 + it * 4 + rr;
      const int byte = (row * 256 + q * 16) ^ ((row & 7) << 4);
      const f16x8 v = *(const f16x8*)((const char*)on + byte);
      float x[8];
#pragma unroll
      for (int e = 0; e < 8; e++) x[e] = (float)v[e];
      float s = 0.f, sq = 0.f;
#pragma unroll
      for (int e = 0; e < 8; e++) { s += x[e]; sq += x[e] * x[e]; }
#pragma unroll
      for (int off = 8; off > 0; off >>= 1) {
        s += __shfl_xor(s, off);
        sq += __shfl_xor(sq, off);
      }
      const float mu = s * (1.0f / 128.0f);
      const float rs = rsqrtf(sq * (1.0f / 128.0f) - mu * mu + 1e-5f);
      f16x8 p;
      p[0] = (f16)((x[0] - mu) * rs * lw0.x + lb0.x);
      p[1] = (f16)((x[1] - mu) * rs * lw0.y + lb0.y);
      p[2] = (f16)((x[2] - mu) * rs * lw0.z + lb0.z);
      p[3] = (f16)((x[3] - mu) * rs * lw0.w + lb0.w);
      p[4] = (f16)((x[4] - mu) * rs * lw1.x + lb1.x);
      p[5] = (f16)((x[5] - mu) * rs * lw1.y + lb1.y);
      p[6] = (f16)((x[6] - mu) * rs * lw1.z + lb1.z);
      p[7] = (f16)((x[7] - mu) * rs * lw1.w + lb1.w);
      *(f16x8*)((char*)on + byte) = p;
    }
  }
  __syncthreads();

  const int g = lane >> 4, ln16 = lane & 15;
  const f16* __restrict__ wg = wq3;
  const f16* __restrict__ wo = wq3 + (size_t)CH * CH;
#pragma unroll
  for (int f = 0; f < 2; f++) {
    const int col = w * 32 + f * 16 + ln16;
    f16x8 bg[4], bo[4];
#pragma unroll
    for (int ks = 0; ks < 4; ks++) {
      const size_t woff = (size_t)col * CH + ks * 32 + g * 8;
      bg[ks] = *(const f16x8*)(wg + woff);
      bo[ks] = *(const f16x8*)(wo + woff);
    }
#pragma unroll
    for (int mt = 0; mt < 4; mt++) {
      const int m0 = mt * 16;
      const int row = m0 + ln16;
      f32x4 accG = {0.f, 0.f, 0.f, 0.f}, accP = {0.f, 0.f, 0.f, 0.f};
#pragma unroll
      for (int ks = 0; ks < 4; ks++) {
        const int byte =
            (row * 256 + (ks * 32 + g * 8) * 2) ^ ((row & 7) << 4);
        const f16x8 az = *(const f16x8*)((const char*)zn + byte);
        const f16x8 ao = *(const f16x8*)((const char*)on + byte);
        accG = __builtin_amdgcn_mfma_f32_16x16x32_f16(az, bg[ks], accG, 0, 0, 0);
        accP = __builtin_amdgcn_mfma_f32_16x16x32_f16(ao, bo[ks], accP, 0, 0, 0);
      }
#pragma unroll
      for (int reg = 0; reg < 4; reg++) {
        const int orow = m0 + g * 4 + reg;
        out[(r0 + orow) * CH + col] = sigmoidf_(accG[reg]) * accP[reg];
      }
    }
  }
}

extern "C" void kernel_launch(void* const* d_in, const int* in_sizes, int n_in,
                              void* d_out, int out_size, void* d_ws, size_t ws_size,
                              hipStream_t stream) {
  const float* z = (const float*)d_in[0];
  const float* pm = (const float*)d_in[1];
  const float* ln_in_w = (const float*)d_in[2];
  const float* ln_in_b = (const float*)d_in[3];
  const float* ln_out_w = (const float*)d_in[4];
  const float* ln_out_b = (const float*)d_in[5];
  const float* w_pa = (const float*)d_in[6];
  const float* w_pb = (const float*)d_in[7];
  const float* w_ga = (const float*)d_in[8];
  const float* w_gb = (const float*)d_in[9];
  const float* w_g = (const float*)d_in[10];
  const float* w_o = (const float*)d_in[11];

  // ws: a_t [0,64MB) | b_t [64,128MB). pass2 overwrites b_t with o16s in
  // place (strip-ownership safe). After pass2: wq3 (64KB) at a_t head.
  // d_out: wq (128KB, pass0->pass1) -> final out (128MB, fused pass3).
  f16* a_t = (f16*)d_ws;
  f16* b_t = a_t + (size_t)CH * NROW;
  float* out = (float*)d_out;
  f16* wq = (f16*)d_out;
  f16* wq3 = (f16*)d_ws;

  k_pass0<<<256, 256, 0, stream>>>(w_pa, w_ga, w_pb, w_gb, wq);
  k_pass1<<<4096, 256, 0, stream>>>(z, pm, ln_in_w, ln_in_b, wq, a_t, b_t);
  k_pass2<<<512, 512, 0, stream>>>(a_t, b_t);
  k_cvt2<<<128, 256, 0, stream>>>(w_g, w_o, wq3);
  k_pass3<<<4096, 256, 0, stream>>>(z, ln_in_w, ln_in_b, ln_out_w, ln_out_b,
                                    b_t, wq3, out);
}